// Round 6
// baseline (8880.264 us; speedup 1.0000x reference)
//
#include <hip/hip_runtime.h>
#include <math.h>

#define BB 32
#define TT 512
#define FF 1024
#define UU 1024
#define NGRP 4
#define GBLK 16
#define MROW 8           // batches per group
#define NBLK (NGRP * GBLK)

typedef __attribute__((ext_vector_type(8))) short s8v;    // 8 x bf16 (4 VGPR)
typedef __attribute__((ext_vector_type(4))) float f4v;    // 4 x f32
typedef __attribute__((ext_vector_type(2))) float f2v;    // 2 x f32
typedef __attribute__((ext_vector_type(2))) unsigned int u2v;

static __device__ __forceinline__ unsigned short f2bf(float f) {
    unsigned int u = __builtin_bit_cast(unsigned int, f);
    u += 0x7fff + ((u >> 16) & 1);          // RNE
    return (unsigned short)(u >> 16);
}
static __device__ __forceinline__ float bf2f(unsigned short b) {
    unsigned int u = ((unsigned int)b) << 16;
    return __builtin_bit_cast(float, u);
}

// ---- device-coherent (agent-scope) accesses: bypass non-coherent L1/L2 ----
static __device__ __forceinline__ s8v ld_b128_sc(const void* p) {
    s8v r;
    asm volatile("global_load_dwordx4 %0, %1, off sc0 sc1" : "=v"(r) : "v"(p));
    return r;
}
static __device__ __forceinline__ f4v ld_f128_sc(const void* p) {
    f4v r;
    asm volatile("global_load_dwordx4 %0, %1, off sc0 sc1" : "=v"(r) : "v"(p));
    return r;
}
static __device__ __forceinline__ f2v ld_f64_sc(const void* p) {
    f2v r;
    asm volatile("global_load_dwordx2 %0, %1, off sc0 sc1" : "=v"(r) : "v"(p));
    return r;
}
static __device__ __forceinline__ void st_b128_sc(void* p, f4v v) {
    asm volatile("global_store_dwordx4 %0, %1, off sc0 sc1" :: "v"(p), "v"(v));
}
static __device__ __forceinline__ void st_b64_sc(void* p, u2v v) {
    asm volatile("global_store_dwordx2 %0, %1, off sc0 sc1" :: "v"(p), "v"(v));
}
static __device__ __forceinline__ void st_f64_sc(void* p, f2v v) {
    asm volatile("global_store_dwordx2 %0, %1, off sc0 sc1" :: "v"(p), "v"(v));
}
static __device__ __forceinline__ void st_b32_sc(void* p, unsigned int v) {
    asm volatile("global_store_dword %0, %1, off sc0 sc1" :: "v"(p), "v"(v));
}
static __device__ __forceinline__ void vm_drain_schedfence() {
    asm volatile("s_waitcnt vmcnt(0)" ::: "memory");
    __builtin_amdgcn_sched_barrier(0);
}

// ---------------------------------------------------------------------------
__global__ __launch_bounds__(256) void cvt_bf16(
    const float* __restrict__ in, unsigned short* __restrict__ out, int n4)
{
    int i = blockIdx.x * 256 + threadIdx.x;
    if (i < n4) {
        float4 v = ((const float4*)in)[i];
        ushort4 o;
        o.x = f2bf(v.x); o.y = f2bf(v.y); o.z = f2bf(v.z); o.w = f2bf(v.w);
        ((ushort4*)out)[i] = o;
    }
}

// ---------------------------------------------------------------------------
template<int ROWS, int COLS>
__global__ __launch_bounds__(256) void transpose_bf16(
    const float* __restrict__ W, unsigned short* __restrict__ WT)
{
    __shared__ float tl[32][33];
    const int tx = threadIdx.x, ty = threadIdx.y;   // block (32, 8)
    const int bx = blockIdx.x, by = blockIdx.y;
    #pragma unroll
    for (int i = 0; i < 4; ++i) {
        int r = by * 32 + ty + i * 8;
        int c = bx * 32 + tx;
        tl[ty + i * 8][tx] = W[(size_t)r * COLS + c];
    }
    __syncthreads();
    #pragma unroll
    for (int i = 0; i < 4; ++i) {
        int n = bx * 32 + ty + i * 8;
        int k = by * 32 + tx;
        WT[(size_t)n * ROWS + k] = f2bf(tl[tx][ty + i * 8]);
    }
}

// ---------------------------------------------------------------------------
__global__ __launch_bounds__(256) void gemm_xproj(
    const unsigned short* __restrict__ A,    // [M][1024]
    const unsigned short* __restrict__ BT,   // [N][2048]
    unsigned short* __restrict__ C,          // [M][N]
    int N)
{
    __shared__ unsigned short Al[128][72];
    __shared__ unsigned short Bl[128][72];
    const int tid  = threadIdx.x;
    const int lane = tid & 63;
    const int wave = tid >> 6;
    const int l15  = lane & 15;
    const int kg   = lane >> 4;
    const int m0   = blockIdx.y * 128;
    const int n0   = blockIdx.x * 128;
    const int rowOff = (wave >> 1) * 64;
    const int colOff = (wave & 1) * 64;

    f4v acc[4][4];
    #pragma unroll
    for (int m = 0; m < 4; ++m)
        #pragma unroll
        for (int n = 0; n < 4; ++n) acc[m][n] = (f4v){0.f, 0.f, 0.f, 0.f};

    for (int k0 = 0; k0 < 1024; k0 += 64) {
        #pragma unroll
        for (int it = 0; it < 4; ++it) {
            int c = tid + it * 256;
            int r = c >> 3, off = (c & 7) * 8;
            *(s8v*)&Al[r][off] = *(const s8v*)(A + (size_t)(m0 + r) * 1024 + k0 + off);
            *(s8v*)&Bl[r][off] = *(const s8v*)(BT + (size_t)(n0 + r) * 2048 + k0 + off);
        }
        __syncthreads();
        #pragma unroll
        for (int ks = 0; ks < 2; ++ks) {
            s8v a[4], b[4];
            #pragma unroll
            for (int m = 0; m < 4; ++m)
                a[m] = *(const s8v*)&Al[rowOff + m * 16 + l15][ks * 32 + kg * 8];
            #pragma unroll
            for (int n = 0; n < 4; ++n)
                b[n] = *(const s8v*)&Bl[colOff + n * 16 + l15][ks * 32 + kg * 8];
            #pragma unroll
            for (int m = 0; m < 4; ++m)
                #pragma unroll
                for (int n = 0; n < 4; ++n)
                    acc[m][n] = __builtin_amdgcn_mfma_f32_16x16x32_bf16(a[m], b[n], acc[m][n], 0, 0, 0);
        }
        __syncthreads();
    }
    #pragma unroll
    for (int m = 0; m < 4; ++m)
        #pragma unroll
        for (int n = 0; n < 4; ++n)
            #pragma unroll
            for (int i = 0; i < 4; ++i) {
                int row = m0 + rowOff + m * 16 + kg * 4 + i;
                int col = n0 + colOff + n * 16 + l15;
                C[(size_t)row * N + col] = f2bf(acc[m][n][i]);
            }
}

// ---------------------------------------------------------------------------
// Group-local barrier (16 blocks): fence-free (data moves via sc0/sc1),
// monotonic counter on a group-private cache line, relaxed spin.
// ---------------------------------------------------------------------------
__device__ __forceinline__ void group_barrier(unsigned* counter, unsigned target, int tid)
{
    asm volatile("s_waitcnt vmcnt(0)" ::: "memory");   // stores visible before arrive
    __syncthreads();
    if (tid == 0) {
        __hip_atomic_fetch_add(counter, 1u, __ATOMIC_RELAXED, __HIP_MEMORY_SCOPE_AGENT);
        while (__hip_atomic_load(counter, __ATOMIC_RELAXED, __HIP_MEMORY_SCOPE_AGENT) < target)
            __builtin_amdgcn_s_sleep(1);
    }
    __syncthreads();
}

// ---------------------------------------------------------------------------
// Persistent GRU, batch-grouped: 4 groups x 16 blocks; group g owns batches
// [g*8, g*8+8) and runs an independent 512-step recurrence with 16-wide
// group barriers. Block gb in group: gate cols [gb*128,+128), cand cols
// [gb*64,+64). M=8 batch rows duplicated into 16-row MFMA tiles.
// State via sc0sc1 (no fences -> L2 stays warm for weights/Xg/Xc).
// ---------------------------------------------------------------------------
__global__ __launch_bounds__(256, 1) void gru_persistent(
    const unsigned short* __restrict__ WgT,   // [2048][2048] bf16
    const unsigned short* __restrict__ WcT,   // [1024][2048] bf16
    const unsigned short* __restrict__ Xgb,   // [B*T][2048] bf16
    const unsigned short* __restrict__ Xcb,   // [B*T][1024] bf16
    const float* __restrict__ bg,             // [2048]
    const float* __restrict__ bc,             // [1024]
    float* __restrict__ h,                    // [32][1024] f32
    unsigned short* __restrict__ hb,          // [32][1024] bf16
    unsigned short* __restrict__ rhb,         // [32][1024] bf16
    float* __restrict__ ub,                   // [32][1024] f32
    float* __restrict__ out,                  // [B][T][U] f32
    unsigned* __restrict__ bar)               // NGRP lines, 64 dwords apart
{
    __shared__ float red[4][8][8][16];        // 16 KB: [wave][ntile][row][col]
    const int tid  = threadIdx.x;
    const int lane = tid & 63;
    const int wave = tid >> 6;
    const int l15  = lane & 15;
    const int kg   = lane >> 4;
    const int grp  = blockIdx.x >> 4;         // / GBLK
    const int gb   = blockIdx.x & 15;
    const int b0   = grp * MROW;
    const int gj0  = gb * 128;                // gate col base (0..1920)
    const int cj0  = gb * 64;                 // cand col base (0..960)
    const int kb   = wave * 256;              // K-slice per wave
    const bool is_r = (gb < 8);               // gate cols < 1024 -> r, else u
    unsigned* cnt  = bar + grp * 64;

    const int arow = b0 + (l15 & 7);          // A row (8 rows duplicated x2)

    // epilogue mapping: 8 rows x (128|64) cols over 256 threads
    const int erow = tid >> 5;                // 0..7
    const int ecg  = tid & 31;                // 0..31
    const int eb   = b0 + erow;
    const int gc   = ecg * 4;                 // gate col offset 0..124
    const int cc2  = ecg * 2;                 // cand col offset 0..62

    const float4 bgv = *(const float4*)(bg + gj0 + gc);
    const float2 bcv = *(const float2*)(bc + cj0 + cc2);

    unsigned epoch = 0;

    for (int t = 0; t < TT; ++t) {
        // ================= phase G: gates =================
        f4v hsl = (f4v){0.f, 0.f, 0.f, 0.f};
        if (is_r) hsl = ld_f128_sc(h + (size_t)eb * UU + gj0 + gc);

        s8v a[8];
        #pragma unroll
        for (int kk = 0; kk < 8; ++kk)
            a[kk] = ld_b128_sc(hb + (size_t)arow * UU + kb + kk * 32 + kg * 8);
        vm_drain_schedfence();

        f4v acc[8];
        #pragma unroll
        for (int n = 0; n < 8; ++n) acc[n] = (f4v){0.f, 0.f, 0.f, 0.f};
        #pragma unroll
        for (int n = 0; n < 8; ++n) {
            s8v bf[8];
            #pragma unroll
            for (int kk = 0; kk < 8; ++kk)
                bf[kk] = *(const s8v*)(WgT + (size_t)(gj0 + n * 16 + l15) * 2048
                                            + 1024 + kb + kk * 32 + kg * 8);
            #pragma unroll
            for (int kk = 0; kk < 8; ++kk)
                acc[n] = __builtin_amdgcn_mfma_f32_16x16x32_bf16(a[kk], bf[kk], acc[n], 0, 0, 0);
        }

        if (kg < 2) {
            #pragma unroll
            for (int n = 0; n < 8; ++n)
                #pragma unroll
                for (int i = 0; i < 4; ++i)
                    red[wave][n][kg * 4 + i][l15] = acc[n][i];
        }
        __syncthreads();

        {
            const int n = gc >> 4, cw = gc & 15;
            f4v pre = *(const f4v*)&red[0][n][erow][cw];
            #pragma unroll
            for (int w = 1; w < 4; ++w) pre += *(const f4v*)&red[w][n][erow][cw];
            ushort4 xg = *(const ushort4*)(Xgb + ((size_t)eb * TT + t) * 2048 + gj0 + gc);
            pre[0] += bf2f(xg.x) + bgv.x;
            pre[1] += bf2f(xg.y) + bgv.y;
            pre[2] += bf2f(xg.z) + bgv.z;
            pre[3] += bf2f(xg.w) + bgv.w;
            float s0 = 1.f / (1.f + __expf(-pre[0]));
            float s1 = 1.f / (1.f + __expf(-pre[1]));
            float s2 = 1.f / (1.f + __expf(-pre[2]));
            float s3 = 1.f / (1.f + __expf(-pre[3]));
            if (is_r) {
                unsigned int lo = (unsigned int)f2bf(s0 * hsl[0]) | ((unsigned int)f2bf(s1 * hsl[1]) << 16);
                unsigned int hi = (unsigned int)f2bf(s2 * hsl[2]) | ((unsigned int)f2bf(s3 * hsl[3]) << 16);
                st_b64_sc(rhb + (size_t)eb * UU + gj0 + gc, (u2v){lo, hi});
            } else {
                st_b128_sc(ub + (size_t)eb * UU + (gj0 - UU) + gc, (f4v){s0, s1, s2, s3});
            }
        }

        // stable-in-G prefetches for phase C (drained by barrier's vmcnt)
        ushort2 xc = *(const ushort2*)(Xcb + ((size_t)eb * TT + t) * 1024 + cj0 + cc2);
        f2v hv = ld_f64_sc(h + (size_t)eb * UU + cj0 + cc2);

        ++epoch;
        group_barrier(cnt, epoch * GBLK, tid);

        // ================= phase C: candidate + update =================
        f2v uv = ld_f64_sc(ub + (size_t)eb * UU + cj0 + cc2);

        s8v ac[8];
        #pragma unroll
        for (int kk = 0; kk < 8; ++kk)
            ac[kk] = ld_b128_sc(rhb + (size_t)arow * UU + kb + kk * 32 + kg * 8);
        vm_drain_schedfence();                // also drains uv

        f4v acc2[4];
        #pragma unroll
        for (int n = 0; n < 4; ++n) acc2[n] = (f4v){0.f, 0.f, 0.f, 0.f};
        #pragma unroll
        for (int n = 0; n < 4; ++n) {
            s8v bf[8];
            #pragma unroll
            for (int kk = 0; kk < 8; ++kk)
                bf[kk] = *(const s8v*)(WcT + (size_t)(cj0 + n * 16 + l15) * 2048
                                            + 1024 + kb + kk * 32 + kg * 8);
            #pragma unroll
            for (int kk = 0; kk < 8; ++kk)
                acc2[n] = __builtin_amdgcn_mfma_f32_16x16x32_bf16(ac[kk], bf[kk], acc2[n], 0, 0, 0);
        }

        if (kg < 2) {
            #pragma unroll
            for (int n = 0; n < 4; ++n)
                #pragma unroll
                for (int i = 0; i < 4; ++i)
                    red[wave][n][kg * 4 + i][l15] = acc2[n][i];
        }
        __syncthreads();

        {
            const int n = cc2 >> 4, cw = cc2 & 15;
            f2v pre2 = *(const f2v*)&red[0][n][erow][cw];
            #pragma unroll
            for (int w = 1; w < 4; ++w) {
                f2v p = *(const f2v*)&red[w][n][erow][cw];
                pre2[0] += p[0]; pre2[1] += p[1];
            }
            float c0 = pre2[0] + bf2f(xc.x) + bcv.x;
            float c1 = pre2[1] + bf2f(xc.y) + bcv.y;
            c0 = fminf(fmaxf(c0, -15.f), 15.f);
            c1 = fminf(fmaxf(c1, -15.f), 15.f);
            float e0 = __expf(2.f * c0), e1 = __expf(2.f * c1);
            float t0 = (e0 - 1.f) / (e0 + 1.f);
            float t1 = (e1 - 1.f) / (e1 + 1.f);
            float hn0 = uv[0] * hv[0] + (1.f - uv[0]) * t0;
            float hn1 = uv[1] * hv[1] + (1.f - uv[1]) * t1;

            st_f64_sc(h + (size_t)eb * UU + cj0 + cc2, (f2v){hn0, hn1});
            st_b32_sc(hb + (size_t)eb * UU + cj0 + cc2,
                      (unsigned int)f2bf(hn0) | ((unsigned int)f2bf(hn1) << 16));
            *(float2*)(out + ((size_t)eb * TT + t) * UU + cj0 + cc2) = make_float2(hn0, hn1);
        }

        ++epoch;
        if (t + 1 < TT) group_barrier(cnt, epoch * GBLK, tid);
    }
}

// ===========================================================================
// Fallback per-step kernels (round-2, verified) — used only if ws too small.
// ===========================================================================
__global__ __launch_bounds__(256) void gru_gates2(
    const unsigned short* __restrict__ hb, const unsigned short* __restrict__ WgT,
    const unsigned short* __restrict__ Xgb, const float* __restrict__ bg,
    const float* __restrict__ h, unsigned short* __restrict__ rhb,
    float* __restrict__ ubuf, int t)
{
    __shared__ unsigned short hb_l[32][1032];
    __shared__ unsigned short Wl[16][1032];
    __shared__ float red[4][32][16];
    const int tid = threadIdx.x, lane = tid & 63, wave = tid >> 6;
    const int l15 = lane & 15, kg = lane >> 4;
    const int j0 = blockIdx.x * 16;
    #pragma unroll
    for (int it = 0; it < 16; ++it) {
        int c = tid + it * 256; int r = c >> 7, off = (c & 127) * 8;
        *(s8v*)&hb_l[r][off] = *(const s8v*)(hb + (size_t)r * 1024 + off);
    }
    #pragma unroll
    for (int it = 0; it < 8; ++it) {
        int c = tid + it * 256; int r = c >> 7, off = (c & 127) * 8;
        *(s8v*)&Wl[r][off] = *(const s8v*)(WgT + (size_t)(j0 + r) * 2048 + 1024 + off);
    }
    __syncthreads();
    f4v acc0 = (f4v){0.f,0.f,0.f,0.f}, acc1 = (f4v){0.f,0.f,0.f,0.f};
    const int kbase = wave * 256;
    #pragma unroll
    for (int kk = 0; kk < 8; ++kk) {
        int k = kbase + kk * 32 + kg * 8;
        s8v a0 = *(const s8v*)&hb_l[l15][k];
        s8v a1 = *(const s8v*)&hb_l[16 + l15][k];
        s8v b  = *(const s8v*)&Wl[l15][k];
        acc0 = __builtin_amdgcn_mfma_f32_16x16x32_bf16(a0, b, acc0, 0, 0, 0);
        acc1 = __builtin_amdgcn_mfma_f32_16x16x32_bf16(a1, b, acc1, 0, 0, 0);
    }
    #pragma unroll
    for (int i = 0; i < 4; ++i) {
        red[wave][kg * 4 + i][l15] = acc0[i];
        red[wave][16 + kg * 4 + i][l15] = acc1[i];
    }
    __syncthreads();
    for (int e = tid; e < 512; e += 256) {
        int b = e >> 4, col = e & 15;
        int j = j0 + col;
        float pre = red[0][b][col] + red[1][b][col] + red[2][b][col] + red[3][b][col];
        pre += bf2f(Xgb[((size_t)b * TT + t) * 2048 + j]) + bg[j];
        float s = 1.f / (1.f + __expf(-pre));
        if (j < UU) rhb[b * UU + j] = f2bf(s * h[b * UU + j]);
        else        ubuf[b * UU + (j - UU)] = s;
    }
}

__global__ __launch_bounds__(256) void gru_cand2(
    const unsigned short* __restrict__ rhb, const unsigned short* __restrict__ WcT,
    const unsigned short* __restrict__ Xcb, const float* __restrict__ bc,
    const float* __restrict__ ubuf, float* __restrict__ h,
    unsigned short* __restrict__ hb, float* __restrict__ out, int t)
{
    __shared__ unsigned short rh_l[32][1032];
    __shared__ unsigned short Wl[16][1032];
    __shared__ float red[4][32][16];
    const int tid = threadIdx.x, lane = tid & 63, wave = tid >> 6;
    const int l15 = lane & 15, kg = lane >> 4;
    const int j0 = blockIdx.x * 16;
    #pragma unroll
    for (int it = 0; it < 16; ++it) {
        int c = tid + it * 256; int r = c >> 7, off = (c & 127) * 8;
        *(s8v*)&rh_l[r][off] = *(const s8v*)(rhb + (size_t)r * 1024 + off);
    }
    #pragma unroll
    for (int it = 0; it < 8; ++it) {
        int c = tid + it * 256; int r = c >> 7, off = (c & 127) * 8;
        *(s8v*)&Wl[r][off] = *(const s8v*)(WcT + (size_t)(j0 + r) * 2048 + 1024 + off);
    }
    __syncthreads();
    f4v acc0 = (f4v){0.f,0.f,0.f,0.f}, acc1 = (f4v){0.f,0.f,0.f,0.f};
    const int kbase = wave * 256;
    #pragma unroll
    for (int kk = 0; kk < 8; ++kk) {
        int k = kbase + kk * 32 + kg * 8;
        s8v a0 = *(const s8v*)&rh_l[l15][k];
        s8v a1 = *(const s8v*)&rh_l[16 + l15][k];
        s8v b  = *(const s8v*)&Wl[l15][k];
        acc0 = __builtin_amdgcn_mfma_f32_16x16x32_bf16(a0, b, acc0, 0, 0, 0);
        acc1 = __builtin_amdgcn_mfma_f32_16x16x32_bf16(a1, b, acc1, 0, 0, 0);
    }
    #pragma unroll
    for (int i = 0; i < 4; ++i) {
        red[wave][kg * 4 + i][l15] = acc0[i];
        red[wave][16 + kg * 4 + i][l15] = acc1[i];
    }
    __syncthreads();
    for (int e = tid; e < 512; e += 256) {
        int b = e >> 4, col = e & 15;
        int j = j0 + col;
        float pre = red[0][b][col] + red[1][b][col] + red[2][b][col] + red[3][b][col];
        pre += bf2f(Xcb[((size_t)b * TT + t) * 1024 + j]) + bc[j];
        float cv = tanhf(pre);
        float u  = ubuf[b * UU + j];
        float hv = h[b * UU + j];
        float hn = u * hv + (1.f - u) * cv;
        h[b * UU + j]  = hn;
        hb[b * UU + j] = f2bf(hn);
        out[((size_t)b * TT + t) * UU + j] = hn;
    }
}

// ===========================================================================
extern "C" void kernel_launch(void* const* d_in, const int* in_sizes, int n_in,
                              void* d_out, int out_size, void* d_ws, size_t ws_size,
                              hipStream_t stream) {
    const float* x  = (const float*)d_in[0];
    const float* Wg = (const float*)d_in[1];
    const float* bg = (const float*)d_in[2];
    const float* Wc = (const float*)d_in[3];
    const float* bc = (const float*)d_in[4];
    float* out = (float*)d_out;

    const size_t XB_B  = (size_t)BB * TT * FF * 2;
    const size_t WGT_B = (size_t)2 * UU * (FF + UU) * 2;
    const size_t WCT_B = (size_t)UU * (FF + UU) * 2;
    const size_t XG_B  = (size_t)BB * TT * 2 * UU * 2;
    const size_t XC_B  = (size_t)BB * TT * UU * 2;
    const size_t H_B   = (size_t)BB * UU * 4;
    const size_t HB_B  = (size_t)BB * UU * 2;
    const size_t BAR_B = 4096;
    const size_t NEED  = XB_B + WGT_B + WCT_B + XG_B + XC_B + H_B + HB_B * 2 + H_B + BAR_B;

    char* p = (char*)d_ws;
    unsigned short* xb  = (unsigned short*)p;            p += XB_B;
    unsigned short* WgT = (unsigned short*)p;            p += WGT_B;
    unsigned short* WcT = (unsigned short*)p;            p += WCT_B;
    unsigned short* Xgb = (unsigned short*)p;            p += XG_B;
    unsigned short* Xcb = (unsigned short*)p;            p += XC_B;
    float*          h   = (float*)p;                     p += H_B;
    unsigned short* hb  = (unsigned short*)p;            p += HB_B;
    unsigned short* rhb = (unsigned short*)p;            p += HB_B;
    float*          ub  = (float*)p;                     p += H_B;
    unsigned*       bar = (unsigned*)p;                  p += BAR_B;

    // ---- one-time prep ----
    cvt_bf16<<<(BB * TT * FF / 4 + 255) / 256, 256, 0, stream>>>(x, xb, BB * TT * FF / 4);
    transpose_bf16<FF + UU, 2 * UU><<<dim3(64, 64), dim3(32, 8), 0, stream>>>(Wg, WgT);
    transpose_bf16<FF + UU, UU>    <<<dim3(32, 64), dim3(32, 8), 0, stream>>>(Wc, WcT);
    gemm_xproj<<<dim3(2 * UU / 128, BB * TT / 128), 256, 0, stream>>>(xb, WgT, Xgb, 2 * UU);
    gemm_xproj<<<dim3(UU / 128,     BB * TT / 128), 256, 0, stream>>>(xb, WcT, Xcb, UU);
    hipMemsetAsync(h,   0, H_B,   stream);
    hipMemsetAsync(hb,  0, HB_B,  stream);
    hipMemsetAsync(bar, 0, BAR_B, stream);

    if (ws_size >= NEED) {
        gru_persistent<<<NBLK, 256, 0, stream>>>(WgT, WcT, Xgb, Xcb, bg, bc,
                                                 h, hb, rhb, ub, out, bar);
    } else {
        for (int t = 0; t < TT; ++t) {
            gru_gates2<<<128, 256, 0, stream>>>(hb, WgT, Xgb, bg, h, rhb, ub, t);
            gru_cand2 <<< 64, 256, 0, stream>>>(rhb, WcT, Xcb, bc, ub, h, hb, out, t);
        }
    }
}

// Round 7
// 5203.859 us; speedup vs baseline: 1.7065x; 1.7065x over previous
//
#include <hip/hip_runtime.h>
#include <math.h>

#define BB 32
#define TT 512
#define FF 1024
#define UU 1024
#define NBLK 64
#define MR 16            // batches per pipeline group (2 groups: A=0..15, B=16..31)

typedef __attribute__((ext_vector_type(8))) short s8v;    // 8 x bf16 (4 VGPR)
typedef __attribute__((ext_vector_type(4))) float f4v;    // 4 x f32
typedef __attribute__((ext_vector_type(2))) float f2v;    // 2 x f32

static __device__ __forceinline__ unsigned short f2bf(float f) {
    unsigned int u = __builtin_bit_cast(unsigned int, f);
    u += 0x7fff + ((u >> 16) & 1);          // RNE
    return (unsigned short)(u >> 16);
}
static __device__ __forceinline__ float bf2f(unsigned short b) {
    unsigned int u = ((unsigned int)b) << 16;
    return __builtin_bit_cast(float, u);
}

// ---- device-coherent (agent-scope) accesses: bypass non-coherent L1/L2 ----
static __device__ __forceinline__ s8v ld_b128_sc(const void* p) {
    s8v r;
    asm volatile("global_load_dwordx4 %0, %1, off sc0 sc1" : "=v"(r) : "v"(p));
    return r;
}
static __device__ __forceinline__ f2v ld_f64_sc(const void* p) {
    f2v r;
    asm volatile("global_load_dwordx2 %0, %1, off sc0 sc1" : "=v"(r) : "v"(p));
    return r;
}
static __device__ __forceinline__ float ld_f32_sc(const void* p) {
    float r;
    asm volatile("global_load_dword %0, %1, off sc0 sc1" : "=v"(r) : "v"(p));
    return r;
}
static __device__ __forceinline__ void st_f64_sc(void* p, f2v v) {
    asm volatile("global_store_dwordx2 %0, %1, off sc0 sc1" :: "v"(p), "v"(v));
}
static __device__ __forceinline__ void st_b32_sc(void* p, unsigned int v) {
    asm volatile("global_store_dword %0, %1, off sc0 sc1" :: "v"(p), "v"(v));
}
static __device__ __forceinline__ void st_f32_sc(void* p, float v) {
    asm volatile("global_store_dword %0, %1, off sc0 sc1" :: "v"(p), "v"(v));
}
static __device__ __forceinline__ void st_u16_sc(void* p, unsigned int v) {
    asm volatile("global_store_short %0, %1, off sc0 sc1" :: "v"(p), "v"(v));
}
static __device__ __forceinline__ void vm_drain_schedfence() {
    asm volatile("s_waitcnt vmcnt(0)" ::: "memory");
    __builtin_amdgcn_sched_barrier(0);
}

// ---------------------------------------------------------------------------
__global__ __launch_bounds__(256) void cvt_bf16(
    const float* __restrict__ in, unsigned short* __restrict__ out, int n4)
{
    int i = blockIdx.x * 256 + threadIdx.x;
    if (i < n4) {
        float4 v = ((const float4*)in)[i];
        ushort4 o;
        o.x = f2bf(v.x); o.y = f2bf(v.y); o.z = f2bf(v.z); o.w = f2bf(v.w);
        ((ushort4*)out)[i] = o;
    }
}

// ---------------------------------------------------------------------------
template<int ROWS, int COLS>
__global__ __launch_bounds__(256) void transpose_bf16(
    const float* __restrict__ W, unsigned short* __restrict__ WT)
{
    __shared__ float tl[32][33];
    const int tx = threadIdx.x, ty = threadIdx.y;   // block (32, 8)
    const int bx = blockIdx.x, by = blockIdx.y;
    #pragma unroll
    for (int i = 0; i < 4; ++i) {
        int r = by * 32 + ty + i * 8;
        int c = bx * 32 + tx;
        tl[ty + i * 8][tx] = W[(size_t)r * COLS + c];
    }
    __syncthreads();
    #pragma unroll
    for (int i = 0; i < 4; ++i) {
        int n = bx * 32 + ty + i * 8;
        int k = by * 32 + tx;
        WT[(size_t)n * ROWS + k] = f2bf(tl[tx][ty + i * 8]);
    }
}

// ---------------------------------------------------------------------------
__global__ __launch_bounds__(256) void gemm_xproj(
    const unsigned short* __restrict__ A,    // [M][1024]
    const unsigned short* __restrict__ BT,   // [N][2048]
    unsigned short* __restrict__ C,          // [M][N]
    int N)
{
    __shared__ unsigned short Al[128][72];
    __shared__ unsigned short Bl[128][72];
    const int tid  = threadIdx.x;
    const int lane = tid & 63;
    const int wave = tid >> 6;
    const int l15  = lane & 15;
    const int kg   = lane >> 4;
    const int m0   = blockIdx.y * 128;
    const int n0   = blockIdx.x * 128;
    const int rowOff = (wave >> 1) * 64;
    const int colOff = (wave & 1) * 64;

    f4v acc[4][4];
    #pragma unroll
    for (int m = 0; m < 4; ++m)
        #pragma unroll
        for (int n = 0; n < 4; ++n) acc[m][n] = (f4v){0.f, 0.f, 0.f, 0.f};

    for (int k0 = 0; k0 < 1024; k0 += 64) {
        #pragma unroll
        for (int it = 0; it < 4; ++it) {
            int c = tid + it * 256;
            int r = c >> 3, off = (c & 7) * 8;
            *(s8v*)&Al[r][off] = *(const s8v*)(A + (size_t)(m0 + r) * 1024 + k0 + off);
            *(s8v*)&Bl[r][off] = *(const s8v*)(BT + (size_t)(n0 + r) * 2048 + k0 + off);
        }
        __syncthreads();
        #pragma unroll
        for (int ks = 0; ks < 2; ++ks) {
            s8v a[4], b[4];
            #pragma unroll
            for (int m = 0; m < 4; ++m)
                a[m] = *(const s8v*)&Al[rowOff + m * 16 + l15][ks * 32 + kg * 8];
            #pragma unroll
            for (int n = 0; n < 4; ++n)
                b[n] = *(const s8v*)&Bl[colOff + n * 16 + l15][ks * 32 + kg * 8];
            #pragma unroll
            for (int m = 0; m < 4; ++m)
                #pragma unroll
                for (int n = 0; n < 4; ++n)
                    acc[m][n] = __builtin_amdgcn_mfma_f32_16x16x32_bf16(a[m], b[n], acc[m][n], 0, 0, 0);
        }
        __syncthreads();
    }
    #pragma unroll
    for (int m = 0; m < 4; ++m)
        #pragma unroll
        for (int n = 0; n < 4; ++n)
            #pragma unroll
            for (int i = 0; i < 4; ++i) {
                int row = m0 + rowOff + m * 16 + kg * 4 + i;
                int col = n0 + colOff + n * 16 + l15;
                C[(size_t)row * N + col] = f2bf(acc[m][n][i]);
            }
}

// ---------------------------------------------------------------------------
// Persistent GRU, 2-group software pipeline. 64 blocks x 256 threads.
// Block owns gate cols [blk*32,+32), cand cols [blk*16,+16)  (SAME for both
// groups -> zero extra weight traffic). Groups A=batches 0..15, B=16..31.
// Split-phase barriers: arrive(cnt) ... other group's compute ... wait(cnt).
// State via sc0sc1 coherent ops; no fences -> L2 stays warm.
// ---------------------------------------------------------------------------
__global__ __launch_bounds__(256, 1) void gru_persistent(
    const unsigned short* __restrict__ WgT,   // [2048][2048] bf16
    const unsigned short* __restrict__ WcT,   // [1024][2048] bf16
    const unsigned short* __restrict__ Xgb,   // [B*T][2048] bf16
    const unsigned short* __restrict__ Xcb,   // [B*T][1024] bf16
    const float* __restrict__ bg,             // [2048]
    const float* __restrict__ bc,             // [1024]
    float* __restrict__ h,                    // [32][1024] f32
    unsigned short* __restrict__ hb,          // [32][1024] bf16
    unsigned short* __restrict__ rhb,         // [32][1024] bf16
    float* __restrict__ ub,                   // [32][1024] f32
    float* __restrict__ out,                  // [B][T][U] f32
    unsigned* __restrict__ bar)               // 2 counters, 256 B apart
{
    __shared__ float red[4][2][16][16];           // 8 KB (reused [4][16][16] in C)
    __shared__ unsigned short wc_l[16 * 1024];    // 32 KB, XOR-swizzled
    const int tid  = threadIdx.x;
    const int lane = tid & 63;
    const int wave = tid >> 6;
    const int l15  = lane & 15;
    const int kg   = lane >> 4;
    const int blk  = blockIdx.x;
    const int gj0  = blk * 32;
    const int cj0  = blk * 16;
    const int kb   = wave * 256;
    const bool is_r = (gj0 < UU);
    unsigned* cA = bar;
    unsigned* cB = bar + 64;

    // ---- stage cand recurrent weights into LDS (once), XOR-swizzled ----
    #pragma unroll
    for (int it = 0; it < 8; ++it) {
        int c   = tid + it * 256;
        int col = c >> 7;
        int k   = (c & 127) * 8;
        s8v w = *(const s8v*)(WcT + (size_t)(cj0 + col) * 2048 + 1024 + k);
        *(s8v*)&wc_l[col * 1024 + (k ^ ((col & 7) << 3))] = w;
    }

    // ---- gate recurrent weight B-fragments in registers ----
    s8v bgf[2][8];
    #pragma unroll
    for (int n = 0; n < 2; ++n)
        #pragma unroll
        for (int kk = 0; kk < 8; ++kk)
            bgf[n][kk] = *(const s8v*)(WgT + (size_t)(gj0 + n * 16 + l15) * 2048
                                            + 1024 + kb + kk * 32 + kg * 8);

    // epilogue mapping: 16 rows x 16 col-units per group-phase
    const int erow = tid >> 4;                // 0..15 (batch within group)
    const int ecp  = tid & 15;                // gate: col-pair; cand: col
    const float2 bgv = *(const float2*)(bg + gj0 + ecp * 2);
    const float  bcs = bc[cj0 + ecp];

    __syncthreads();                          // wc_l ready

    auto arrive = [&](unsigned* cnt) {
        asm volatile("s_waitcnt vmcnt(0)" ::: "memory");   // drain sc stores/reads
        __syncthreads();
        if (tid == 0)
            __hip_atomic_fetch_add(cnt, 1u, __ATOMIC_RELAXED, __HIP_MEMORY_SCOPE_AGENT);
    };
    auto wait = [&](unsigned* cnt, unsigned tgt) {
        if (tid == 0)
            while (__hip_atomic_load(cnt, __ATOMIC_RELAXED, __HIP_MEMORY_SCOPE_AGENT) < tgt)
                __builtin_amdgcn_s_sleep(1);
        __syncthreads();
    };

    int t = 0;
    float hvA = 0.f, hvB = 0.f;               // h at cand col (for C epilogue)
    unsigned short xcA = 0, xcB = 0;          // Xc at cand col
    ushort2 xgA = *(const ushort2*)(Xgb + ((size_t)(0  + erow) * TT) * 2048 + gj0 + ecp * 2);
    ushort2 xgB = *(const ushort2*)(Xgb + ((size_t)(MR + erow) * TT) * 2048 + gj0 + ecp * 2);

    auto phaseG = [&](int b0, ushort2 xg, float& hv, unsigned short& xc, unsigned* cnt) {
        // prefetch C-phase operands (h/Xc stable during G)
        xc = Xcb[((size_t)(b0 + erow) * TT + t) * 1024 + cj0 + ecp];
        hv = ld_f32_sc(h + (size_t)(b0 + erow) * UU + cj0 + ecp);
        f2v hsl = (f2v){0.f, 0.f};
        if (is_r) hsl = ld_f64_sc(h + (size_t)(b0 + erow) * UU + gj0 + ecp * 2);

        s8v a[8];
        #pragma unroll
        for (int kk = 0; kk < 8; ++kk)
            a[kk] = ld_b128_sc(hb + (size_t)(b0 + l15) * UU + kb + kk * 32 + kg * 8);
        vm_drain_schedfence();

        f4v acc[2];
        acc[0] = (f4v){0.f, 0.f, 0.f, 0.f};
        acc[1] = (f4v){0.f, 0.f, 0.f, 0.f};
        #pragma unroll
        for (int kk = 0; kk < 8; ++kk) {
            acc[0] = __builtin_amdgcn_mfma_f32_16x16x32_bf16(a[kk], bgf[0][kk], acc[0], 0, 0, 0);
            acc[1] = __builtin_amdgcn_mfma_f32_16x16x32_bf16(a[kk], bgf[1][kk], acc[1], 0, 0, 0);
        }
        #pragma unroll
        for (int n = 0; n < 2; ++n)
            #pragma unroll
            for (int i = 0; i < 4; ++i)
                red[wave][n][kg * 4 + i][l15] = acc[n][i];
        __syncthreads();

        const int n = ecp >> 3, cw = (ecp & 7) * 2;
        float2 pre = *(const float2*)&red[0][n][erow][cw];
        #pragma unroll
        for (int w = 1; w < 4; ++w) {
            float2 p = *(const float2*)&red[w][n][erow][cw];
            pre.x += p.x; pre.y += p.y;
        }
        pre.x += bf2f(xg.x) + bgv.x;
        pre.y += bf2f(xg.y) + bgv.y;
        float s0 = 1.f / (1.f + __expf(-pre.x));
        float s1 = 1.f / (1.f + __expf(-pre.y));
        if (is_r) {
            unsigned int packed = (unsigned int)f2bf(s0 * hsl[0])
                                | ((unsigned int)f2bf(s1 * hsl[1]) << 16);
            st_b32_sc(rhb + (size_t)(b0 + erow) * UU + gj0 + ecp * 2, packed);
        } else {
            st_f64_sc(ub + (size_t)(b0 + erow) * UU + (gj0 - UU) + ecp * 2, (f2v){s0, s1});
        }
        arrive(cnt);
    };

    auto phaseC = [&](int b0, float hv, unsigned short xc, ushort2& xg, unsigned* cnt) {
        float uv = ld_f32_sc(ub + (size_t)(b0 + erow) * UU + cj0 + ecp);
        s8v ac[8];
        #pragma unroll
        for (int kk = 0; kk < 8; ++kk)
            ac[kk] = ld_b128_sc(rhb + (size_t)(b0 + l15) * UU + kb + kk * 32 + kg * 8);
        // prefetch next step's Xg (cached load; completes during spin)
        int tn = (t + 1 < TT) ? t + 1 : t;
        xg = *(const ushort2*)(Xgb + ((size_t)(b0 + erow) * TT + tn) * 2048 + gj0 + ecp * 2);
        vm_drain_schedfence();

        f4v acc2 = (f4v){0.f, 0.f, 0.f, 0.f};
        #pragma unroll
        for (int kk = 0; kk < 8; ++kk) {
            s8v bcf = *(const s8v*)&wc_l[l15 * 1024 + ((kb + kk * 32 + kg * 8) ^ ((l15 & 7) << 3))];
            acc2 = __builtin_amdgcn_mfma_f32_16x16x32_bf16(ac[kk], bcf, acc2, 0, 0, 0);
        }
        float* redc = (float*)red;            // [4][16][16]
        #pragma unroll
        for (int i = 0; i < 4; ++i)
            redc[((size_t)wave * 16 + kg * 4 + i) * 16 + l15] = acc2[i];
        __syncthreads();

        float pre = redc[(0 * 16 + erow) * 16 + ecp];
        #pragma unroll
        for (int w = 1; w < 4; ++w) pre += redc[((size_t)w * 16 + erow) * 16 + ecp];
        float cv = pre + bf2f(xc) + bcs;
        cv = fminf(fmaxf(cv, -15.f), 15.f);
        float e = __expf(2.f * cv);
        float th = (e - 1.f) / (e + 1.f);
        float hn = uv * hv + (1.f - uv) * th;

        st_f32_sc(h + (size_t)(b0 + erow) * UU + cj0 + ecp, hn);
        st_u16_sc(hb + (size_t)(b0 + erow) * UU + cj0 + ecp, (unsigned int)f2bf(hn));
        out[((size_t)(b0 + erow) * TT + t) * UU + cj0 + ecp] = hn;
        arrive(cnt);
    };

    for (t = 0; t < TT; ++t) {
        const unsigned base = (unsigned)(2 * t) * NBLK;
        wait(cA, base);                 // h_A(t-1) fully written
        phaseG(0, xgA, hvA, xcA, cA);   // -> cA = base + NBLK
        wait(cB, base);                 // h_B(t-1) ready (overlaps G_A's roundtrip)
        phaseG(MR, xgB, hvB, xcB, cB);  // -> cB = base + NBLK
        wait(cA, base + NBLK);          // rhb_A / ub_A ready
        phaseC(0, hvA, xcA, xgA, cA);   // -> cA = base + 2*NBLK
        wait(cB, base + NBLK);          // rhb_B / ub_B ready
        phaseC(MR, hvB, xcB, xgB, cB);  // -> cB = base + 2*NBLK
    }
}

// ===========================================================================
// Fallback per-step kernels (round-2, verified) — used only if ws too small.
// ===========================================================================
__global__ __launch_bounds__(256) void gru_gates2(
    const unsigned short* __restrict__ hb, const unsigned short* __restrict__ WgT,
    const unsigned short* __restrict__ Xgb, const float* __restrict__ bg,
    const float* __restrict__ h, unsigned short* __restrict__ rhb,
    float* __restrict__ ubuf, int t)
{
    __shared__ unsigned short hb_l[32][1032];
    __shared__ unsigned short Wl[16][1032];
    __shared__ float red[4][32][16];
    const int tid = threadIdx.x, lane = tid & 63, wave = tid >> 6;
    const int l15 = lane & 15, kg = lane >> 4;
    const int j0 = blockIdx.x * 16;
    #pragma unroll
    for (int it = 0; it < 16; ++it) {
        int c = tid + it * 256; int r = c >> 7, off = (c & 127) * 8;
        *(s8v*)&hb_l[r][off] = *(const s8v*)(hb + (size_t)r * 1024 + off);
    }
    #pragma unroll
    for (int it = 0; it < 8; ++it) {
        int c = tid + it * 256; int r = c >> 7, off = (c & 127) * 8;
        *(s8v*)&Wl[r][off] = *(const s8v*)(WgT + (size_t)(j0 + r) * 2048 + 1024 + off);
    }
    __syncthreads();
    f4v acc0 = (f4v){0.f,0.f,0.f,0.f}, acc1 = (f4v){0.f,0.f,0.f,0.f};
    const int kbase = wave * 256;
    #pragma unroll
    for (int kk = 0; kk < 8; ++kk) {
        int k = kbase + kk * 32 + kg * 8;
        s8v a0 = *(const s8v*)&hb_l[l15][k];
        s8v a1 = *(const s8v*)&hb_l[16 + l15][k];
        s8v b  = *(const s8v*)&Wl[l15][k];
        acc0 = __builtin_amdgcn_mfma_f32_16x16x32_bf16(a0, b, acc0, 0, 0, 0);
        acc1 = __builtin_amdgcn_mfma_f32_16x16x32_bf16(a1, b, acc1, 0, 0, 0);
    }
    #pragma unroll
    for (int i = 0; i < 4; ++i) {
        red[wave][kg * 4 + i][l15] = acc0[i];
        red[wave][16 + kg * 4 + i][l15] = acc1[i];
    }
    __syncthreads();
    for (int e = tid; e < 512; e += 256) {
        int b = e >> 4, col = e & 15;
        int j = j0 + col;
        float pre = red[0][b][col] + red[1][b][col] + red[2][b][col] + red[3][b][col];
        pre += bf2f(Xgb[((size_t)b * TT + t) * 2048 + j]) + bg[j];
        float s = 1.f / (1.f + __expf(-pre));
        if (j < UU) rhb[b * UU + j] = f2bf(s * h[b * UU + j]);
        else        ubuf[b * UU + (j - UU)] = s;
    }
}

__global__ __launch_bounds__(256) void gru_cand2(
    const unsigned short* __restrict__ rhb, const unsigned short* __restrict__ WcT,
    const unsigned short* __restrict__ Xcb, const float* __restrict__ bc,
    const float* __restrict__ ubuf, float* __restrict__ h,
    unsigned short* __restrict__ hb, float* __restrict__ out, int t)
{
    __shared__ unsigned short rh_l[32][1032];
    __shared__ unsigned short Wl[16][1032];
    __shared__ float red[4][32][16];
    const int tid = threadIdx.x, lane = tid & 63, wave = tid >> 6;
    const int l15 = lane & 15, kg = lane >> 4;
    const int j0 = blockIdx.x * 16;
    #pragma unroll
    for (int it = 0; it < 16; ++it) {
        int c = tid + it * 256; int r = c >> 7, off = (c & 127) * 8;
        *(s8v*)&rh_l[r][off] = *(const s8v*)(rhb + (size_t)r * 1024 + off);
    }
    #pragma unroll
    for (int it = 0; it < 8; ++it) {
        int c = tid + it * 256; int r = c >> 7, off = (c & 127) * 8;
        *(s8v*)&Wl[r][off] = *(const s8v*)(WcT + (size_t)(j0 + r) * 2048 + 1024 + off);
    }
    __syncthreads();
    f4v acc0 = (f4v){0.f,0.f,0.f,0.f}, acc1 = (f4v){0.f,0.f,0.f,0.f};
    const int kbase = wave * 256;
    #pragma unroll
    for (int kk = 0; kk < 8; ++kk) {
        int k = kbase + kk * 32 + kg * 8;
        s8v a0 = *(const s8v*)&rh_l[l15][k];
        s8v a1 = *(const s8v*)&rh_l[16 + l15][k];
        s8v b  = *(const s8v*)&Wl[l15][k];
        acc0 = __builtin_amdgcn_mfma_f32_16x16x32_bf16(a0, b, acc0, 0, 0, 0);
        acc1 = __builtin_amdgcn_mfma_f32_16x16x32_bf16(a1, b, acc1, 0, 0, 0);
    }
    #pragma unroll
    for (int i = 0; i < 4; ++i) {
        red[wave][kg * 4 + i][l15] = acc0[i];
        red[wave][16 + kg * 4 + i][l15] = acc1[i];
    }
    __syncthreads();
    for (int e = tid; e < 512; e += 256) {
        int b = e >> 4, col = e & 15;
        int j = j0 + col;
        float pre = red[0][b][col] + red[1][b][col] + red[2][b][col] + red[3][b][col];
        pre += bf2f(Xcb[((size_t)b * TT + t) * 1024 + j]) + bc[j];
        float cv = tanhf(pre);
        float u  = ubuf[b * UU + j];
        float hv = h[b * UU + j];
        float hn = u * hv + (1.f - u) * cv;
        h[b * UU + j]  = hn;
        hb[b * UU + j] = f2bf(hn);
        out[((size_t)b * TT + t) * UU + j] = hn;
    }
}

// ===========================================================================
extern "C" void kernel_launch(void* const* d_in, const int* in_sizes, int n_in,
                              void* d_out, int out_size, void* d_ws, size_t ws_size,
                              hipStream_t stream) {
    const float* x  = (const float*)d_in[0];
    const float* Wg = (const float*)d_in[1];
    const float* bg = (const float*)d_in[2];
    const float* Wc = (const float*)d_in[3];
    const float* bc = (const float*)d_in[4];
    float* out = (float*)d_out;

    const size_t XB_B  = (size_t)BB * TT * FF * 2;
    const size_t WGT_B = (size_t)2 * UU * (FF + UU) * 2;
    const size_t WCT_B = (size_t)UU * (FF + UU) * 2;
    const size_t XG_B  = (size_t)BB * TT * 2 * UU * 2;
    const size_t XC_B  = (size_t)BB * TT * UU * 2;
    const size_t H_B   = (size_t)BB * UU * 4;
    const size_t HB_B  = (size_t)BB * UU * 2;
    const size_t BAR_B = 4096;
    const size_t NEED  = XB_B + WGT_B + WCT_B + XG_B + XC_B + H_B + HB_B * 2 + H_B + BAR_B;

    char* p = (char*)d_ws;
    unsigned short* xb  = (unsigned short*)p;            p += XB_B;
    unsigned short* WgT = (unsigned short*)p;            p += WGT_B;
    unsigned short* WcT = (unsigned short*)p;            p += WCT_B;
    unsigned short* Xgb = (unsigned short*)p;            p += XG_B;
    unsigned short* Xcb = (unsigned short*)p;            p += XC_B;
    float*          h   = (float*)p;                     p += H_B;
    unsigned short* hb  = (unsigned short*)p;            p += HB_B;
    unsigned short* rhb = (unsigned short*)p;            p += HB_B;
    float*          ub  = (float*)p;                     p += H_B;
    unsigned*       bar = (unsigned*)p;                  p += BAR_B;

    // ---- one-time prep ----
    cvt_bf16<<<(BB * TT * FF / 4 + 255) / 256, 256, 0, stream>>>(x, xb, BB * TT * FF / 4);
    transpose_bf16<FF + UU, 2 * UU><<<dim3(64, 64), dim3(32, 8), 0, stream>>>(Wg, WgT);
    transpose_bf16<FF + UU, UU>    <<<dim3(32, 64), dim3(32, 8), 0, stream>>>(Wc, WcT);
    gemm_xproj<<<dim3(2 * UU / 128, BB * TT / 128), 256, 0, stream>>>(xb, WgT, Xgb, 2 * UU);
    gemm_xproj<<<dim3(UU / 128,     BB * TT / 128), 256, 0, stream>>>(xb, WcT, Xcb, UU);
    hipMemsetAsync(h,   0, H_B,   stream);
    hipMemsetAsync(hb,  0, HB_B,  stream);
    hipMemsetAsync(bar, 0, BAR_B, stream);

    if (ws_size >= NEED) {
        gru_persistent<<<NBLK, 256, 0, stream>>>(WgT, WcT, Xgb, Xcb, bg, bc,
                                                 h, hb, rhb, ub, out, bar);
    } else {
        for (int t = 0; t < TT; ++t) {
            gru_gates2<<<128, 256, 0, stream>>>(hb, WgT, Xgb, bg, h, rhb, ub, t);
            gru_cand2 <<< 64, 256, 0, stream>>>(rhb, WcT, Xcb, bc, ub, h, hb, out, t);
        }
    }
}